// Round 8
// baseline (121.095 us; speedup 1.0000x reference)
//
#include <hip/hip_runtime.h>
#include <math.h>

// DifferentiableKalmanCell: B=4096, STATE=64, OBS=32, coeffs (64,64,11), t scalar.
// One block per batch; MFMA (bf16 split hi/lo) for all GEMM phases; S^-1 by
// single-wave register Gauss-Jordan.
// R8: cut VALU work (the measured floor):
//   - Chebyshev/dCheb LDS tables built once per block (kills the 64x-redundant
//     per-(o,i) recurrence in p1).
//   - prep kernel pre-splits H into bf16 hi/lo in d_ws (+ exp(q), exp(r));
//     p4/p5 load b16x8 from global (L2-hot), no split8v.
//   - barrier B2 removed (sy+residual wave0-local, same-wave LDS order).
// LDS 40704 B => still 4 blocks/CU.
//   @0     P-split(u16) -> T(u32 packed) -> PHt|K        (16384)
//   @16384 F-split(u16) -> cov(u32 packed)               (16384)
//   @32768 ypart[256] (dead after p1-epilogue)           (1024)
//   @32768 sS f32[32][36] (written at p5)                (4608)
//   @33792 chT f32[64][12] | @36864 dcT f32[64][12] (dead after B1) (6144)
//   @39936 sy,sresid,sq,sr                               (768) => 40704

typedef float f4 __attribute__((ext_vector_type(4)));
typedef float f32x4 __attribute__((ext_vector_type(4)));
typedef short b16x8 __attribute__((ext_vector_type(8)));
typedef short b16x4 __attribute__((ext_vector_type(4)));
typedef unsigned int u32;
typedef unsigned int u32x4 __attribute__((ext_vector_type(4)));
typedef unsigned short u16;

#define EPSC 1e-7f
#define MFMA(a, b, c) __builtin_amdgcn_mfma_f32_16x16x32_bf16(a, b, c, 0, 0, 0)
static constexpr size_t CU_OFF = 4096 * 64;
static constexpr size_t CD_OFF = CU_OFF + 4096ull * 4096;

__device__ __forceinline__ void split2(float x, short &h, short &l) {
  u32 u = __float_as_uint(x);
  h = (short)(u >> 16);
  float rem = x - __uint_as_float(u & 0xffff0000u);
  l = (short)(__float_as_uint(rem) >> 16);
}
__device__ __forceinline__ u32 packsplit(float x) {
  u32 u = __float_as_uint(x) & 0xffff0000u;
  float rem = x - __uint_as_float(u);
  return u | (__float_as_uint(rem) >> 16);
}
__device__ __forceinline__ float unpackf(u32 v) {
  return __uint_as_float(v & 0xffff0000u) + __uint_as_float(v << 16);
}
union U8 { u32x4 u; b16x8 s; };
__device__ __forceinline__ void unpack8(u32x4 q0, u32x4 q1, b16x8 &hi,
                                        b16x8 &lo) {
  U8 H, L;
  H.u[0] = __builtin_amdgcn_perm(q0[1], q0[0], 0x07060302u);
  H.u[1] = __builtin_amdgcn_perm(q0[3], q0[2], 0x07060302u);
  H.u[2] = __builtin_amdgcn_perm(q1[1], q1[0], 0x07060302u);
  H.u[3] = __builtin_amdgcn_perm(q1[3], q1[2], 0x07060302u);
  L.u[0] = __builtin_amdgcn_perm(q0[1], q0[0], 0x05040100u);
  L.u[1] = __builtin_amdgcn_perm(q0[3], q0[2], 0x05040100u);
  L.u[2] = __builtin_amdgcn_perm(q1[1], q1[0], 0x05040100u);
  L.u[3] = __builtin_amdgcn_perm(q1[3], q1[2], 0x05040100u);
  hi = H.s;
  lo = L.s;
}
__device__ __forceinline__ void split8v(f4 a, f4 b, b16x8 &hi, b16x8 &lo) {
#pragma unroll
  for (int j = 0; j < 4; ++j) {
    short hh, ll;
    split2(a[j], hh, ll); hi[j] = hh; lo[j] = ll;
    split2(b[j], hh, ll); hi[4 + j] = hh; lo[4 + j] = ll;
  }
}

// ---- prep: H -> bf16 hi/lo split in ws; q = exp(logQ), r = exp(logR).
// ws: Hh u16[2048] @0 | Hl @4096B | q f32[64] @8192B | r f32[32] @8448B
__global__ __launch_bounds__(256) void prep_kernel(
    const float *__restrict__ Hm, const float *__restrict__ logQ,
    const float *__restrict__ logR, void *__restrict__ ws) {
  u16 *Hh = (u16 *)ws;
  u16 *Hl = (u16 *)ws + 2048;
  float *wq = (float *)((char *)ws + 8192);
  float *wr = wq + 64;
  const int tid = (int)threadIdx.x;
  f4 a = *(const f4 *)(Hm + tid * 8);
  f4 b = *(const f4 *)(Hm + tid * 8 + 4);
  b16x8 hi, lo;
  split8v(a, b, hi, lo);
  *(b16x8 *)(Hh + tid * 8) = hi;
  *(b16x8 *)(Hl + tid * 8) = lo;
  if (tid < 64) wq[tid] = expf(logQ[tid]);
  else if (tid < 96) wr[tid - 64] = expf(logR[tid - 64]);
}

__global__ __launch_bounds__(256, 4) void kalman_fused(
    const float *__restrict__ obs, const float *__restrict__ prev_state,
    const float *__restrict__ prev_cov, const float *__restrict__ coeffs,
    const float *__restrict__ Hm, const int *__restrict__ tptr,
    const void *__restrict__ ws, float *__restrict__ out) {
  __shared__ __align__(16) unsigned char pool[40704];
  u16 *sPh = (u16 *)(pool);
  u16 *sPl = (u16 *)(pool + 8192);
  u32 *sT = (u32 *)(pool);
  u32 *sPHt = (u32 *)(pool);
  u32 *sK = (u32 *)(pool + 8192);
  u16 *sFh = (u16 *)(pool + 16384);
  u16 *sFl = (u16 *)(pool + 24576);
  u32 *sCov = (u32 *)(pool + 16384);
  float *ypart = (float *)(pool + 32768);  // dead after p1 epilogue
  float *sS = (float *)(pool + 32768);     // written at p5
  float *sChT = (float *)(pool + 33792);   // [64][12], dead after B1
  float *sDcT = (float *)(pool + 36864);   // [64][12], dead after B1
  float *sy = (float *)(pool + 39936);
  float *sresid = (float *)(pool + 40192);
  float *sq = (float *)(pool + 40320);
  float *sr = (float *)(pool + 40576);

  const u16 *wHh = (const u16 *)ws;
  const u16 *wHl = (const u16 *)ws + 2048;
  const float *wq = (const float *)((const char *)ws + 8192);
  const float *wr = wq + 64;

  const int tid = (int)threadIdx.x;
  const int b = (int)blockIdx.x;
  const int w = tid >> 6;
  const int l = tid & 63;
  const int lr = l & 15;
  const int h = l >> 4;

  // degree(t): D = degree+1 = 9 + int(1 + sin(2*pi*t/95)), D in 9..11
  const int tval = tptr[0];
  const float ang = 6.28318530717958647f * ((float)tval / 95.0f);
  const int D = 9 + (int)(1.0f + sinf(ang));

  // ---- p0: stage P (bf16 hi/lo split, swizzled); q/r loads; cheb tables
  {
    const float *Pg = prev_cov + (size_t)b * 4096;
#pragma unroll
    for (int e = 0; e < 4; ++e) {
      const int idx = tid + 256 * e;
      f4 v = *(const f4 *)(Pg + 4 * idx);
      const int r = idx >> 4, c = (idx & 15) * 4;
      const int x = (r & 7) << 3;
      b16x4 h4, l4;
#pragma unroll
      for (int j = 0; j < 4; ++j) {
        short hh, ll;
        split2(v[j], hh, ll);
        h4[j] = hh; l4[j] = ll;
      }
      *(b16x4 *)(sPh + r * 64 + (c ^ x)) = h4;
      *(b16x4 *)(sPl + r * 64 + (c ^ x)) = l4;
    }
    if (tid < 64) {
      sq[tid] = wq[tid];
      const float xx = prev_state[b * 64 + tid];
      const float tr_ = tanhf(xx);
      const float tv = fminf(fmaxf(tr_, -1.0f + EPSC), 1.0f - EPSC);
      const float sn = sqrtf(fmaxf(1.0f - tv * tv, 0.0f));
      const float mask = (tr_ > -1.0f + EPSC && tr_ < 1.0f - EPSC) ? 1.0f : 0.0f;
      const float dth = -(1.0f - tr_ * tr_) * mask / sn;
      float *ct = sChT + tid * 12;
      float *dt = sDcT + tid * 12;
      ct[0] = 1.f; ct[1] = tv; ct[11] = 0.f;
      dt[0] = 0.f; dt[1] = -dth * sn; dt[11] = 0.f;
      float cm2 = 1.f, cm1 = tv, sm2 = 0.f, sm1 = sn;
      const float tv2 = 2.f * tv;
#pragma unroll
      for (int d = 2; d <= 10; ++d) {
        const float cc = fmaf(tv2, cm1, -cm2);
        const float ss = fmaf(tv2, sm1, -sm2);
        ct[d] = (d < D) ? cc : 0.f;
        dt[d] = (d < D) ? (-dth * (float)d * ss) : 0.f;
        cm2 = cm1; cm1 = cc; sm2 = sm1; sm1 = ss;
      }
    } else if (tid < 96) {
      sr[tid - 64] = wr[tid - 64];
    }
  }
  __syncthreads(); // B0

  // ---- p1: y partials + Jacobian F via table broadcast; F -> split swz
  {
    const int o = tid & 63, g = tid >> 6;
    float yacc = 0.f;
    float fr[16];
#pragma unroll
    for (int ii = 0; ii < 16; ++ii) {
      const int i = g * 16 + ii;
      const float *cp = coeffs + (size_t)(i * 64 + o) * 11;
      f4 q0 = *(const f4 *)(cp);
      f4 q1 = *(const f4 *)(cp + 4);
      f4 q2 = *(const f4 *)(cp + 7); // q2[1..3] = cp[8..10]
      const float *ct = sChT + i * 12;
      const float *dt = sDcT + i * 12;
      f4 c0 = *(const f4 *)(ct), c1 = *(const f4 *)(ct + 4),
         c2 = *(const f4 *)(ct + 8);
      f4 e0 = *(const f4 *)(dt), e1 = *(const f4 *)(dt + 4),
         e2 = *(const f4 *)(dt + 8);
      float yac = q0[0]; // ch[0] == 1
      yac = fmaf(q0[1], c0[1], yac);
      yac = fmaf(q0[2], c0[2], yac);
      yac = fmaf(q0[3], c0[3], yac);
      yac = fmaf(q1[0], c1[0], yac);
      yac = fmaf(q1[1], c1[1], yac);
      yac = fmaf(q1[2], c1[2], yac);
      yac = fmaf(q1[3], c1[3], yac);
      yac = fmaf(q2[1], c2[0], yac);
      yac = fmaf(q2[2], c2[1], yac);
      yac = fmaf(q2[3], c2[2], yac);
      float fra = q0[1] * e0[1]; // dch[0] == 0
      fra = fmaf(q0[2], e0[2], fra);
      fra = fmaf(q0[3], e0[3], fra);
      fra = fmaf(q1[0], e1[0], fra);
      fra = fmaf(q1[1], e1[1], fra);
      fra = fmaf(q1[2], e1[2], fra);
      fra = fmaf(q1[3], e1[3], fra);
      fra = fmaf(q2[1], e2[0], fra);
      fra = fmaf(q2[2], e2[1], fra);
      fra = fmaf(q2[3], e2[2], fra);
      yacc += yac;
      fr[ii] = fra;
    }
    b16x8 fh0, fh1, fl0, fl1;
#pragma unroll
    for (int j = 0; j < 8; ++j) {
      short hh, ll;
      split2(fr[j], hh, ll); fh0[j] = hh; fl0[j] = ll;
      split2(fr[8 + j], hh, ll); fh1[j] = hh; fl1[j] = ll;
    }
    const int x = (o & 7) << 3;
    *(b16x8 *)(sFh + o * 64 + ((g * 16) ^ x)) = fh0;
    *(b16x8 *)(sFh + o * 64 + ((g * 16 + 8) ^ x)) = fh1;
    *(b16x8 *)(sFl + o * 64 + ((g * 16) ^ x)) = fl0;
    *(b16x8 *)(sFl + o * 64 + ((g * 16 + 8) ^ x)) = fl1;
    ypart[g * 64 + o] = yacc;
  }
  __syncthreads(); // B1

  // ---- sy + residual: wave 0 only; same-wave LDS ordering (no barrier)
  if (tid < 64) {
    sy[tid] = ypart[tid] + ypart[64 + tid] + ypart[128 + tid] +
              ypart[192 + tid];
  }
  __builtin_amdgcn_wave_barrier(); // keep sy writes before residual reads
  if (tid < 32) {
    float racc = obs[b * 32 + tid];
    const float *Hr = Hm + tid * 64;
#pragma unroll
    for (int s = 0; s < 64; s += 4) {
      f4 hv = *(const f4 *)(Hr + s);
      racc -= hv[0] * sy[s] + hv[1] * sy[s + 1] + hv[2] * sy[s + 2] +
              hv[3] * sy[s + 3];
    }
    sresid[tid] = racc;
  }

  // ---- p2 (MFMA): T = F * P (P symmetric -> B-frag = row read)
  f32x4 accT[4] = {{0.f, 0.f, 0.f, 0.f}, {0.f, 0.f, 0.f, 0.f},
                   {0.f, 0.f, 0.f, 0.f}, {0.f, 0.f, 0.f, 0.f}};
  {
    const int m = 16 * w + lr;
    const int xA = (m & 7) << 3;
#pragma unroll
    for (int kc = 0; kc < 2; ++kc) {
      const int k = kc * 32 + h * 8;
      b16x8 Ah = *(const b16x8 *)(sFh + m * 64 + (k ^ xA));
      b16x8 Al = *(const b16x8 *)(sFl + m * 64 + (k ^ xA));
#pragma unroll
      for (int t = 0; t < 4; ++t) {
        const int n = t * 16 + lr;
        const int xB = (n & 7) << 3;
        b16x8 Bh = *(const b16x8 *)(sPh + n * 64 + (k ^ xB));
        b16x8 Bl = *(const b16x8 *)(sPl + n * 64 + (k ^ xB));
        accT[t] = MFMA(Ah, Bh, accT[t]);
        accT[t] = MFMA(Al, Bh, accT[t]);
        accT[t] = MFMA(Ah, Bl, accT[t]);
      }
    }
  }
  __syncthreads(); // B3: P reads drained; overwrite with packed T
  {
    const int r0 = 16 * w + h * 4;
#pragma unroll
    for (int t = 0; t < 4; ++t)
#pragma unroll
      for (int j = 0; j < 4; ++j) {
        const int rr = r0 + j, cc = t * 16 + lr;
        sT[rr * 64 + (cc ^ ((rr & 7) << 2))] = packsplit(accT[t][j]);
      }
  }

  // ---- p3 (MFMA): cov_pred = T * F^T + diag(q). A = T band-local.
  f32x4 accC[4] = {{0.f, 0.f, 0.f, 0.f}, {0.f, 0.f, 0.f, 0.f},
                   {0.f, 0.f, 0.f, 0.f}, {0.f, 0.f, 0.f, 0.f}};
  {
    const int m = 16 * w + lr;
    const int xA = (m & 7) << 2;
    const u32 *Tb = sT + m * 64;
#pragma unroll
    for (int kc = 0; kc < 2; ++kc) {
      const int k = kc * 32 + h * 8;
      u32x4 q0 = *(const u32x4 *)(Tb + (k ^ xA));
      u32x4 q1 = *(const u32x4 *)(Tb + ((k + 4) ^ xA));
      b16x8 Ah, Al;
      unpack8(q0, q1, Ah, Al);
#pragma unroll
      for (int t = 0; t < 4; ++t) {
        const int n = t * 16 + lr;
        const int xB = (n & 7) << 3;
        b16x8 Bh = *(const b16x8 *)(sFh + n * 64 + (k ^ xB));
        b16x8 Bl = *(const b16x8 *)(sFl + n * 64 + (k ^ xB));
        accC[t] = MFMA(Ah, Bh, accC[t]);
        accC[t] = MFMA(Al, Bh, accC[t]);
        accC[t] = MFMA(Ah, Bl, accC[t]);
      }
    }
  }
  __syncthreads(); // B4: F and T reads drained; overwrite F with packed cov
  {
    const int r0 = 16 * w + h * 4;
#pragma unroll
    for (int t = 0; t < 4; ++t)
#pragma unroll
      for (int j = 0; j < 4; ++j) {
        const int rr = r0 + j, cc = t * 16 + lr;
        float v = accC[t][j];
        if (rr == cc) v += sq[rr];
        sCov[rr * 64 + (cc ^ ((rr & 7) << 2))] = packsplit(v);
      }
  }

  // ---- p4 (MFMA): PHt = cov_pred * H^T (A = cov band-local; B = ws H-split)
  {
    f32x4 acc[2] = {{0.f, 0.f, 0.f, 0.f}, {0.f, 0.f, 0.f, 0.f}};
    const int m = 16 * w + lr;
    const int xA = (m & 7) << 2;
    const u32 *Cb = sCov + m * 64;
#pragma unroll
    for (int kc = 0; kc < 2; ++kc) {
      const int k = kc * 32 + h * 8;
      u32x4 q0 = *(const u32x4 *)(Cb + (k ^ xA));
      u32x4 q1 = *(const u32x4 *)(Cb + ((k + 4) ^ xA));
      b16x8 Ah, Al;
      unpack8(q0, q1, Ah, Al);
#pragma unroll
      for (int t = 0; t < 2; ++t) {
        const int n = t * 16 + lr;
        b16x8 Bh = *(const b16x8 *)(wHh + n * 64 + k);
        b16x8 Bl = *(const b16x8 *)(wHl + n * 64 + k);
        acc[t] = MFMA(Ah, Bh, acc[t]);
        acc[t] = MFMA(Al, Bh, acc[t]);
        acc[t] = MFMA(Ah, Bl, acc[t]);
      }
    }
    const int r0 = 16 * w + h * 4;
#pragma unroll
    for (int t = 0; t < 2; ++t)
#pragma unroll
      for (int j = 0; j < 4; ++j) {
        const int rr = r0 + j, cc = t * 16 + lr;
        sPHt[rr * 32 + (cc ^ ((rr & 7) << 2))] = packsplit(acc[t][j]);
      }
  }
  __syncthreads(); // B5

  // ---- p5 (MFMA): S = H * PHt + diag(r); wave w -> tile (w>>1, w&1)
  {
    const int tr = w >> 1, tc = w & 1;
    f32x4 acc = {0.f, 0.f, 0.f, 0.f};
    const int m = tr * 16 + lr;
    const int n = tc * 16 + lr;
#pragma unroll
    for (int kc = 0; kc < 2; ++kc) {
      const int k = kc * 32 + h * 8;
      b16x8 Ah = *(const b16x8 *)(wHh + m * 64 + k);
      b16x8 Al = *(const b16x8 *)(wHl + m * 64 + k);
      u32x4 q0, q1;
#pragma unroll
      for (int j = 0; j < 4; ++j)
        q0[j] = sPHt[(k + j) * 32 + (n ^ (j << 2))];
#pragma unroll
      for (int j = 0; j < 4; ++j)
        q1[j] = sPHt[(k + 4 + j) * 32 + (n ^ ((4 + j) << 2))];
      b16x8 Bh, Bl;
      unpack8(q0, q1, Bh, Bl);
      acc = MFMA(Ah, Bh, acc);
      acc = MFMA(Al, Bh, acc);
      acc = MFMA(Ah, Bl, acc);
    }
    const int r0 = tr * 16 + h * 4;
#pragma unroll
    for (int j = 0; j < 4; ++j) {
      const int rr = r0 + j, cc = tc * 16 + lr;
      float v = acc[j];
      if (rr == cc) v += sr[rr];
      sS[rr * 36 + cc] = v;
    }
  }
  __syncthreads(); // B6

  // ---- p6: S^-1 in-register Gauss-Jordan on wave 0 (no pivoting, SPD>=I).
  if (w == 0) {
    const int mr = l >> 1, half = l & 1;
    float s0[16];
    const float *gbase = sS + mr * 36 + half * 16;
    {
      f4 v0 = *(const f4 *)(gbase + 0), v1 = *(const f4 *)(gbase + 4);
      f4 v2 = *(const f4 *)(gbase + 8), v3 = *(const f4 *)(gbase + 12);
#pragma unroll
      for (int j = 0; j < 4; ++j) {
        s0[j] = v0[j]; s0[4 + j] = v1[j]; s0[8 + j] = v2[j]; s0[12 + j] = v3[j];
      }
    }
#pragma unroll
    for (int p = 0; p < 32; ++p) {
      const int ph = p >> 4, pi = p & 15;
      float prow[16];
#pragma unroll
      for (int j = 0; j < 16; ++j) prow[j] = __shfl(s0[j], 2 * p + half, 64);
      const float dpp = __shfl(s0[pi], 2 * p + ph, 64);
      const float d = 1.0f / dpp;
      const float fv = __shfl(s0[pi], (l & 62) + ph, 64);
      if (mr == p) {
#pragma unroll
        for (int j = 0; j < 16; ++j) s0[j] = prow[j] * d;
        if (half == ph) s0[pi] = d;
      } else {
        const float fd = fv * d;
#pragma unroll
        for (int j = 0; j < 16; ++j) s0[j] = fmaf(-fd, prow[j], s0[j]);
        if (half == ph) s0[pi] = -fd;
      }
    }
    float *wbase = sS + mr * 36 + half * 16;
    f4 w0 = {s0[0], s0[1], s0[2], s0[3]};
    f4 w1 = {s0[4], s0[5], s0[6], s0[7]};
    f4 w2 = {s0[8], s0[9], s0[10], s0[11]};
    f4 w3 = {s0[12], s0[13], s0[14], s0[15]};
    *(f4 *)(wbase + 0) = w0;
    *(f4 *)(wbase + 4) = w1;
    *(f4 *)(wbase + 8) = w2;
    *(f4 *)(wbase + 12) = w3;
  }
  __syncthreads(); // B7

  // ---- p7 (MFMA): K = PHt * S^-1 (B row-read via S^-1 symmetry)
  {
    f32x4 acc[2] = {{0.f, 0.f, 0.f, 0.f}, {0.f, 0.f, 0.f, 0.f}};
    const int m = 16 * w + lr;
    const int xA = (m & 7) << 2;
    const int k = h * 8;
    u32x4 q0 = *(const u32x4 *)(sPHt + m * 32 + (k ^ xA));
    u32x4 q1 = *(const u32x4 *)(sPHt + m * 32 + ((k + 4) ^ xA));
    b16x8 Ah, Al;
    unpack8(q0, q1, Ah, Al);
#pragma unroll
    for (int t = 0; t < 2; ++t) {
      const int n = t * 16 + lr;
      f4 b0 = *(const f4 *)(sS + n * 36 + k);
      f4 b1 = *(const f4 *)(sS + n * 36 + k + 4);
      b16x8 Bh, Bl;
      split8v(b0, b1, Bh, Bl);
      acc[t] = MFMA(Ah, Bh, acc[t]);
      acc[t] = MFMA(Al, Bh, acc[t]);
      acc[t] = MFMA(Ah, Bl, acc[t]);
    }
    const int r0 = 16 * w + h * 4;
#pragma unroll
    for (int t = 0; t < 2; ++t)
#pragma unroll
      for (int j = 0; j < 4; ++j) {
        const int rr = r0 + j, cc = t * 16 + lr;
        sK[rr * 32 + (cc ^ ((rr & 7) << 2))] = packsplit(acc[t][j]);
      }
  }
  __syncthreads(); // B8

  // ---- p8: state_update (wave 0) + cov_update = cov_pred - K*PHt^T (MFMA)
  if (tid < 64) {
    float su = sy[tid];
    const int x = (tid & 7) << 2;
    const u32 *Kb = sK + tid * 32;
#pragma unroll
    for (int c0 = 0; c0 < 32; c0 += 4) {
      u32x4 q = *(const u32x4 *)(Kb + (c0 ^ x));
#pragma unroll
      for (int j = 0; j < 4; ++j)
        su = fmaf(unpackf(q[j]), sresid[c0 + j], su);
    }
    out[b * 64 + tid] = su;
  }
  {
    const int m = 16 * w + lr;
    const int xA = (m & 7) << 2;
    const int k = h * 8;
    u32x4 q0 = *(const u32x4 *)(sK + m * 32 + (k ^ xA));
    u32x4 q1 = *(const u32x4 *)(sK + m * 32 + ((k + 4) ^ xA));
#pragma unroll
    for (int j = 0; j < 4; ++j) { // negate both halves: -K
      q0[j] ^= 0x80008000u;
      q1[j] ^= 0x80008000u;
    }
    b16x8 Ah, Al;
    unpack8(q0, q1, Ah, Al);
    const int r0 = 16 * w + h * 4;
    float *outc = out + CU_OFF + (size_t)b * 4096;
#pragma unroll
    for (int t = 0; t < 4; ++t) {
      const int n = t * 16 + lr;
      const int xB = (n & 7) << 2;
      u32x4 p0 = *(const u32x4 *)(sPHt + n * 32 + (k ^ xB));
      u32x4 p1 = *(const u32x4 *)(sPHt + n * 32 + ((k + 4) ^ xB));
      b16x8 Bh, Bl;
      unpack8(p0, p1, Bh, Bl);
      f32x4 acc;
#pragma unroll
      for (int j = 0; j < 4; ++j) {
        const int rr = r0 + j;
        acc[j] = unpackf(sCov[rr * 64 + (n ^ ((rr & 7) << 2))]);
      }
      acc = MFMA(Ah, Bh, acc);
      acc = MFMA(Al, Bh, acc);
      acc = MFMA(Ah, Bl, acc);
#pragma unroll
      for (int j = 0; j < 4; ++j) {
        const int rr = r0 + j;
        outc[rr * 64 + n] = acc[j];
        if (rr == n) out[CD_OFF + b * 64 + rr] = acc[j];
      }
    }
  }
}

extern "C" void kernel_launch(void *const *d_in, const int *in_sizes, int n_in,
                              void *d_out, int out_size, void *d_ws,
                              size_t ws_size, hipStream_t stream) {
  const float *obs = (const float *)d_in[0];
  const float *prev_state = (const float *)d_in[1];
  const float *prev_cov = (const float *)d_in[2];
  const float *coeffs = (const float *)d_in[3];
  const float *Hm = (const float *)d_in[4];
  const float *logQ = (const float *)d_in[5];
  const float *logR = (const float *)d_in[6];
  const int *tptr = (const int *)d_in[7];
  (void)in_sizes; (void)n_in; (void)out_size; (void)ws_size;
  prep_kernel<<<dim3(1), dim3(256), 0, stream>>>(Hm, logQ, logR, d_ws);
  kalman_fused<<<dim3(4096), dim3(256), 0, stream>>>(
      obs, prev_state, prev_cov, coeffs, Hm, tptr, d_ws, (float *)d_out);
}